// Round 16
// baseline (1473.849 us; speedup 1.0000x reference)
//
#include <hip/hip_runtime.h>
#include <hip/hip_bf16.h>

// GNN_84043920048593: hetero SAGEConv. f32 I/O.
// R14 best: 540us. R15 regression root-caused: dual-source global A-stream
// thrashed L1 (FETCH 57->587MB). R16: fuse gather into epilogues — A rows
// gathered into padded LDS, GEMM reads A from LDS (R14 inner structure).
// Eliminates agg HBM roundtrips (~200MB) and 3 kernel launches.

typedef unsigned int u32;
typedef unsigned char u8;

__global__ void sentinel_kernel(float* out, int n) {
    int i = blockIdx.x * 256 + threadIdx.x;
    if (i < n) out[i] = 999.0f;
}

// ---------- CSR build (unchanged, validated R13) ----------------------------
__global__ void __launch_bounds__(256)
bin_hist_kernel(const int* __restrict__ dst, int* __restrict__ binhist,
                int n, int shift) {
    __shared__ int lh[256];
    int tid = threadIdx.x;
    lh[tid] = 0;
    __syncthreads();
    int base = blockIdx.x * 4096;
    #pragma unroll
    for (int k = 0; k < 16; ++k) {
        int e = base + k * 256 + tid;
        if (e < n) atomicAdd(&lh[dst[e] >> shift], 1);
    }
    __syncthreads();
    if (lh[tid] > 0) atomicAdd(binhist + tid, lh[tid]);
}

__global__ void __launch_bounds__(256)
bin_scan_kernel(const int* __restrict__ binhist, int* __restrict__ start,
                int* __restrict__ cur_bin, int nbins) {
    __shared__ int sh[256];
    int t = threadIdx.x;
    int v = (t < nbins) ? binhist[t] : 0;
    sh[t] = v;
    __syncthreads();
    for (int off = 1; off < 256; off <<= 1) {
        int u = (t >= off) ? sh[t - off] : 0;
        __syncthreads();
        sh[t] += u;
        __syncthreads();
    }
    if (t < nbins) { start[t] = sh[t] - v; cur_bin[t] = sh[t] - v; }
    if (t == 255) start[nbins] = sh[255];
}

__global__ void __launch_bounds__(256)
bin_scatter_kernel(const int* __restrict__ src, const int* __restrict__ dst,
                   const int* __restrict__ remap,
                   int* __restrict__ cur_bin, u32* __restrict__ staging,
                   int n, int shift) {
    __shared__ int lh[256], sc[256], lrp[256], lcur[256], lbase[256];
    __shared__ u32 stage[4096];
    __shared__ u8  sbin[4096];
    int tid = threadIdx.x;
    lh[tid] = 0;
    __syncthreads();
    int base = blockIdx.x * 4096;
    int mybin[16]; u32 mypk[16];
    int dmask = (1 << shift) - 1;
    #pragma unroll
    for (int k = 0; k < 16; ++k) {
        int e = base + k * 256 + tid;
        mybin[k] = -1;
        if (e < n) {
            int d = dst[e];
            int s = src[e];
            if (remap) s = remap[s];
            int b = d >> shift;
            mybin[k] = b;
            mypk[k] = ((u32)(d & dmask) << 18) | (u32)s;
            atomicAdd(&lh[b], 1);
        }
    }
    __syncthreads();
    int v = lh[tid];
    sc[tid] = v;
    __syncthreads();
    for (int off = 1; off < 256; off <<= 1) {
        int u = (tid >= off) ? sc[tid - off] : 0;
        __syncthreads();
        sc[tid] += u;
        __syncthreads();
    }
    lrp[tid] = sc[tid] - v;
    lcur[tid] = sc[tid] - v;
    if (v > 0) lbase[tid] = atomicAdd(&cur_bin[tid], v);
    __syncthreads();
    #pragma unroll
    for (int k = 0; k < 16; ++k) {
        if (mybin[k] >= 0) {
            int p = atomicAdd(&lcur[mybin[k]], 1);
            stage[p] = mypk[k];
            sbin[p] = (u8)mybin[k];
        }
    }
    __syncthreads();
    int cnt_here = min(4096, n - base);
    for (int i = tid; i < cnt_here; i += 256) {
        int b = sbin[i];
        staging[lbase[b] + (i - lrp[b])] = stage[i];
    }
}

__global__ void __launch_bounds__(256)
bin_build_kernel(const u32* __restrict__ staging, const int* __restrict__ start,
                 int* __restrict__ bucket, int* __restrict__ rp,
                 int* __restrict__ cnt, int shift, int n_dst) {
    __shared__ int fh[1024], frp[1024], fcur[1024], part[256];
    int tid = threadIdx.x;
    int b = blockIdx.x;
    int s0 = start[b], s1 = start[b + 1];
    int m = s1 - s0;
    int nd = 1 << shift;
    int dbase = b << shift;
    for (int j = tid; j < nd; j += 256) fh[j] = 0;
    __syncthreads();
    for (int i = tid; i < m; i += 256)
        atomicAdd(&fh[staging[s0 + i] >> 18], 1);
    __syncthreads();
    int K = nd >> 8;
    int t0 = tid * K;
    int s = 0;
    for (int k = 0; k < K; ++k) s += fh[t0 + k];
    part[tid] = s;
    __syncthreads();
    for (int off = 1; off < 256; off <<= 1) {
        int u = (tid >= off) ? part[tid - off] : 0;
        __syncthreads();
        part[tid] += u;
        __syncthreads();
    }
    int run = part[tid] - s;
    for (int k = 0; k < K; ++k) {
        frp[t0 + k] = run; fcur[t0 + k] = run;
        run += fh[t0 + k];
    }
    __syncthreads();
    for (int j = tid; j < nd; j += 256) {
        int d = dbase + j;
        if (d < n_dst) { rp[d] = s0 + frp[j]; cnt[d] = fh[j]; }
    }
    for (int i = tid; i < m; i += 256) {
        u32 pk = staging[s0 + i];
        int dl = pk >> 18;
        int p = atomicAdd(&fcur[dl], 1);
        bucket[s0 + p] = (int)(pk & 0x3FFFFu);
    }
}

// ---------- helpers ---------------------------------------------------------
#define LOADW(WB, Wp)                                                       \
    for (int idx = threadIdx.x; idx < 4096; idx += 256) {                   \
        int k = idx >> 6, j = idx & 63;                                     \
        WB[k][j] = (Wp)[j * 64 + k];                                        \
    }
#define LOADW2(WB, Wp, Wq)                                                  \
    for (int idx = threadIdx.x; idx < 4096; idx += 256) {                   \
        int k = idx >> 6, j = idx & 63;                                     \
        WB[k][j] = (Wp)[j * 64 + k] + (Wq)[j * 64 + k];                     \
    }

// gather one dst row's mean into LDS row (wave-cooperative, 4 edge slots)
__device__ __forceinline__ void gather_row(const float* __restrict__ x,
                                           const int* __restrict__ rp,
                                           const int* __restrict__ cnt,
                                           const int* __restrict__ bkt,
                                           int grow, int n_dst,
                                           float* arow, int q, int c)
{
    float4 acc = make_float4(0.f, 0.f, 0.f, 0.f);
    int deg = 0;
    if (grow < n_dst) {
        int st = rp[grow];
        deg = cnt[grow];
        for (int j = 0; j < deg; j += 4) {
            int idx = j + q;
            int r = bkt[st + min(idx, deg - 1)];
            float m = (idx < deg) ? 1.0f : 0.0f;
            float4 v = ((const float4*)x)[(size_t)r * 16 + c];
            acc.x += m * v.x; acc.y += m * v.y;
            acc.z += m * v.z; acc.w += m * v.w;
        }
    }
    acc.x += __shfl_xor(acc.x, 16); acc.y += __shfl_xor(acc.y, 16);
    acc.z += __shfl_xor(acc.z, 16); acc.w += __shfl_xor(acc.w, 16);
    acc.x += __shfl_xor(acc.x, 32); acc.y += __shfl_xor(acc.y, 32);
    acc.z += __shfl_xor(acc.z, 32); acc.w += __shfl_xor(acc.w, 32);
    if (q == 0) {
        float inv = 1.0f / fmaxf((float)deg, 1.0f);
        *(float4*)(arow + c * 4) =
            make_float4(acc.x * inv, acc.y * inv, acc.z * inv, acc.w * inv);
    }
}

// ---------- fused label: gather(tl,ll)->LDS, 3 GEMM phases ------------------
// Block = 64 rows; thread (ty=tid>>4, tx=tid&15) owns 4 rows x 4 cols.
__global__ void __launch_bounds__(256, 3)
fused_label_kernel(const float* __restrict__ title_x,
                   const float* __restrict__ label_emb,
                   const int* __restrict__ rp_tl, const int* __restrict__ cnt_tl,
                   const int* __restrict__ bkt_tl,
                   const int* __restrict__ rp_ll, const int* __restrict__ cnt_ll,
                   const int* __restrict__ bkt_ll,
                   const int* __restrict__ nid,
                   const float* __restrict__ Wl_tl, const float* __restrict__ bl_tl,
                   const float* __restrict__ Wr_tl,
                   const float* __restrict__ Wl_ll, const float* __restrict__ bl_ll,
                   const float* __restrict__ Wr_ll,
                   float* __restrict__ out, int n)
{
    __shared__ float atl[64][68];    // +4 pad: rows 4 apart land on distinct banks
    __shared__ float all_[64][68];
    __shared__ float wbuf[64][64];

    int tid = threadIdx.x;
    int wave = tid >> 6, lane = tid & 63;
    int q = lane >> 4, c = lane & 15;
    int base = blockIdx.x * 64;

    // gather: 128 row-tasks (64 tl + 64 ll), 32 per wave
    for (int t = wave * 32; t < wave * 32 + 32; ++t) {
        int lrow = t & 63;
        if (t < 64)
            gather_row(title_x,  rp_tl, cnt_tl, bkt_tl, base + lrow, n, atl[lrow], q, c);
        else
            gather_row(label_emb, rp_ll, cnt_ll, bkt_ll, base + lrow, n, all_[lrow], q, c);
    }
    LOADW(wbuf, Wl_tl)          // independent of gather LDS regions
    __syncthreads();

    int ty = tid >> 4, tx = tid & 15;
    int j0 = tx * 4;
    int lr0 = ty * 4;

    int nd[4];
    #pragma unroll
    for (int r = 0; r < 4; ++r) nd[r] = nid[min(base + lr0 + r, n - 1)];

    float acc[4][4];
    #pragma unroll
    for (int r = 0; r < 4; ++r)
        #pragma unroll
        for (int cc = 0; cc < 4; ++cc)
            acc[r][cc] = bl_tl[j0 + cc] + bl_ll[j0 + cc];

    // phase 0: atl x Wl_tl^T
    for (int kb = 0; kb < 64; kb += 4) {
        float4 a[4];
        #pragma unroll
        for (int r = 0; r < 4; ++r) a[r] = *(const float4*)(&atl[lr0 + r][kb]);
        #pragma unroll
        for (int kk = 0; kk < 4; ++kk) {
            float4 w = *(const float4*)(&wbuf[kb + kk][j0]);
            #pragma unroll
            for (int r = 0; r < 4; ++r) {
                float av = ((const float*)&a[r])[kk];
                acc[r][0] += av * w.x; acc[r][1] += av * w.y;
                acc[r][2] += av * w.z; acc[r][3] += av * w.w;
            }
        }
    }
    __syncthreads();
    LOADW(wbuf, Wl_ll)
    __syncthreads();

    // phase 1: all_ x Wl_ll^T
    for (int kb = 0; kb < 64; kb += 4) {
        float4 a[4];
        #pragma unroll
        for (int r = 0; r < 4; ++r) a[r] = *(const float4*)(&all_[lr0 + r][kb]);
        #pragma unroll
        for (int kk = 0; kk < 4; ++kk) {
            float4 w = *(const float4*)(&wbuf[kb + kk][j0]);
            #pragma unroll
            for (int r = 0; r < 4; ++r) {
                float av = ((const float*)&a[r])[kk];
                acc[r][0] += av * w.x; acc[r][1] += av * w.y;
                acc[r][2] += av * w.z; acc[r][3] += av * w.w;
            }
        }
    }
    __syncthreads();
    LOADW2(wbuf, Wr_tl, Wr_ll)
    __syncthreads();

    // phase 2: x_label (global, nid rows) x (Wr_tl+Wr_ll)^T
    for (int kb = 0; kb < 64; kb += 4) {
        float4 a[4];
        #pragma unroll
        for (int r = 0; r < 4; ++r)
            a[r] = *(const float4*)(label_emb + (size_t)nd[r] * 64 + kb);
        #pragma unroll
        for (int kk = 0; kk < 4; ++kk) {
            float4 w = *(const float4*)(&wbuf[kb + kk][j0]);
            #pragma unroll
            for (int r = 0; r < 4; ++r) {
                float av = ((const float*)&a[r])[kk];
                acc[r][0] += av * w.x; acc[r][1] += av * w.y;
                acc[r][2] += av * w.z; acc[r][3] += av * w.w;
            }
        }
    }

    #pragma unroll
    for (int r = 0; r < 4; ++r) {
        int gi = base + lr0 + r;
        if (gi < n) {
            float4 o;
            o.x = fmaxf(acc[r][0], 0.0f); o.y = fmaxf(acc[r][1], 0.0f);
            o.z = fmaxf(acc[r][2], 0.0f); o.w = fmaxf(acc[r][3], 0.0f);
            *(float4*)(out + (size_t)gi * 64 + j0) = o;
        }
    }
}

// ---------- fused title: gather(lt)->LDS, 2 GEMM phases ---------------------
// Block = 128 rows; thread (ty=tid>>4, tx=tid&15) owns 8 rows x 4 cols.
__global__ void __launch_bounds__(256, 3)
fused_title_kernel(const float* __restrict__ label_emb,
                   const float* __restrict__ title_x,
                   const int* __restrict__ rp, const int* __restrict__ cnt,
                   const int* __restrict__ bkt,
                   const float* __restrict__ Wl_tl, const float* __restrict__ bl_tl,
                   const float* __restrict__ Wr_tl,
                   float* __restrict__ out, int n)
{
    __shared__ float alt[128][68];
    __shared__ float wbuf[64][64];

    int tid = threadIdx.x;
    int wave = tid >> 6, lane = tid & 63;
    int q = lane >> 4, c = lane & 15;
    int base = blockIdx.x * 128;

    for (int t = wave * 32; t < wave * 32 + 32; ++t)
        gather_row(label_emb, rp, cnt, bkt, base + t, n, alt[t], q, c);
    LOADW(wbuf, Wl_tl)
    __syncthreads();

    int ty = tid >> 4, tx = tid & 15;
    int j0 = tx * 4;
    int lr0 = ty * 8;

    float acc[8][4];
    #pragma unroll
    for (int r = 0; r < 8; ++r)
        #pragma unroll
        for (int cc = 0; cc < 4; ++cc)
            acc[r][cc] = bl_tl[j0 + cc];

    // phase 0: alt x Wl_tl^T (A from LDS)
    for (int kb = 0; kb < 64; kb += 4) {
        float4 a[8];
        #pragma unroll
        for (int r = 0; r < 8; ++r) a[r] = *(const float4*)(&alt[lr0 + r][kb]);
        #pragma unroll
        for (int kk = 0; kk < 4; ++kk) {
            float4 w = *(const float4*)(&wbuf[kb + kk][j0]);
            #pragma unroll
            for (int r = 0; r < 8; ++r) {
                float av = ((const float*)&a[r])[kk];
                acc[r][0] += av * w.x; acc[r][1] += av * w.y;
                acc[r][2] += av * w.z; acc[r][3] += av * w.w;
            }
        }
    }
    __syncthreads();
    LOADW(wbuf, Wr_tl)
    __syncthreads();

    // phase 1: title_x (global, own rows) x Wr_tl^T
    int rr[8];
    #pragma unroll
    for (int r = 0; r < 8; ++r) rr[r] = min(base + lr0 + r, n - 1);
    for (int kb = 0; kb < 64; kb += 4) {
        float4 a[8];
        #pragma unroll
        for (int r = 0; r < 8; ++r)
            a[r] = *(const float4*)(title_x + (size_t)rr[r] * 64 + kb);
        #pragma unroll
        for (int kk = 0; kk < 4; ++kk) {
            float4 w = *(const float4*)(&wbuf[kb + kk][j0]);
            #pragma unroll
            for (int r = 0; r < 8; ++r) {
                float av = ((const float*)&a[r])[kk];
                acc[r][0] += av * w.x; acc[r][1] += av * w.y;
                acc[r][2] += av * w.z; acc[r][3] += av * w.w;
            }
        }
    }

    #pragma unroll
    for (int r = 0; r < 8; ++r) {
        int gi = base + lr0 + r;
        if (gi < n) {
            float4 o;
            o.x = fmaxf(acc[r][0], 0.0f); o.y = fmaxf(acc[r][1], 0.0f);
            o.z = fmaxf(acc[r][2], 0.0f); o.w = fmaxf(acc[r][3], 0.0f);
            *(float4*)(out + (size_t)gi * 64 + j0) = o;
        }
    }
}

extern "C" void kernel_launch(void* const* d_in, const int* in_sizes, int n_in,
                              void* d_out, int out_size, void* d_ws, size_t ws_size,
                              hipStream_t stream)
{
    const float* title_x   = (const float*)d_in[0];
    const float* label_emb = (const float*)d_in[1];
    const float* Wl_tl     = (const float*)d_in[2];
    const float* bl_tl     = (const float*)d_in[3];
    const float* Wr_tl     = (const float*)d_in[4];
    const float* Wl_ll     = (const float*)d_in[5];
    const float* bl_ll     = (const float*)d_in[6];
    const float* Wr_ll     = (const float*)d_in[7];
    const int* label_node_id = (const int*)d_in[8];
    const int* tl_src = (const int*)d_in[9];
    const int* tl_dst = (const int*)d_in[10];
    const int* lt_src = (const int*)d_in[11];
    const int* lt_dst = (const int*)d_in[12];
    const int* ll_src = (const int*)d_in[13];
    const int* ll_dst = (const int*)d_in[14];

    const int NT  = in_sizes[0] / 64;
    const int NL  = in_sizes[8];
    const int eTL = in_sizes[9];
    const int eLT = in_sizes[11];
    const int eLL = in_sizes[13];

    const int SH_L = 9,  NB_L = (NL + 511) >> 9;
    const int SH_T = 10, NB_T = (NT + 1023) >> 10;

    size_t iNL = (size_t)NL * 4;
    size_t iNT = (size_t)NT * 4;
    size_t max_e = (size_t)(eTL > eLL ? (eTL > eLT ? eTL : eLT)
                                      : (eLL > eLT ? eLL : eLT));

    // phase A region: bkt_tl | bkt_ll | rp_tl | cnt_tl | rp_ll | cnt_ll
    size_t regionA = ((size_t)eTL + eLL) * 4 + 4 * iNL;
    // phase B region (overlays A): bkt_lt | rp_lt | cnt_lt
    size_t regionB = (size_t)eLT * 4 + 2 * iNT;
    size_t big     = regionA > regionB ? regionA : regionB;
    size_t szStag  = max_e * 4;
    size_t szSmall = (256 + 257 + 256) * 4;
    size_t needed  = big + szStag + szSmall;

    float* out_label = (float*)d_out;
    float* out_title = out_label + (size_t)NL * 64;

    if (ws_size < needed) {
        sentinel_kernel<<<(out_size + 255) / 256, 256, 0, stream>>>((float*)d_out, out_size);
        return;
    }

    char* base = (char*)d_ws;
    // phase A layout
    int* bkt_tl = (int*)(base);
    int* bkt_ll = bkt_tl + eTL;
    int* rp_tl  = (int*)(base + ((size_t)eTL + eLL) * 4);
    int* cnt_tl = rp_tl + NL;
    int* rp_ll  = cnt_tl + NL;
    int* cnt_ll = rp_ll + NL;
    // phase B layout (overlays A; stream-ordered)
    int* bkt_lt = (int*)(base);
    int* rp_lt  = (int*)(base + (size_t)eLT * 4);
    int* cnt_lt = rp_lt + NT;
    // shared tail
    u32* staging = (u32*)(base + big);
    int* binhist = (int*)(base + big + szStag);
    int* startb  = binhist + 256;
    int* curbin  = startb + 257;

    auto nchunk = [](int n) { return (n + 4095) / 4096; };

    auto build_csr = [&](const int* esrc, const int* edst, const int* remap,
                         int* bucket, int* rp, int* cnt,
                         int n_edges, int n_dst, int shift, int nbins) {
        (void)hipMemsetAsync(binhist, 0, nbins * 4, stream);
        bin_hist_kernel<<<nchunk(n_edges), 256, 0, stream>>>(edst, binhist, n_edges, shift);
        bin_scan_kernel<<<1, 256, 0, stream>>>(binhist, startb, curbin, nbins);
        bin_scatter_kernel<<<nchunk(n_edges), 256, 0, stream>>>(
            esrc, edst, remap, curbin, staging, n_edges, shift);
        bin_build_kernel<<<nbins, 256, 0, stream>>>(
            staging, startb, bucket, rp, cnt, shift, n_dst);
    };

    // ---- phase A: label destination ----------------------------------------
    build_csr(tl_src, tl_dst, nullptr,       bkt_tl, rp_tl, cnt_tl, eTL, NL, SH_L, NB_L);
    build_csr(ll_src, ll_dst, label_node_id, bkt_ll, rp_ll, cnt_ll, eLL, NL, SH_L, NB_L);
    fused_label_kernel<<<(NL + 63) / 64, 256, 0, stream>>>(
        title_x, label_emb, rp_tl, cnt_tl, bkt_tl, rp_ll, cnt_ll, bkt_ll,
        label_node_id, Wl_tl, bl_tl, Wr_tl, Wl_ll, bl_ll, Wr_ll, out_label, NL);

    // ---- phase B: title destination (stream-ordered reuse) -----------------
    build_csr(lt_src, lt_dst, label_node_id, bkt_lt, rp_lt, cnt_lt, eLT, NT, SH_T, NB_T);
    fused_title_kernel<<<(NT + 127) / 128, 256, 0, stream>>>(
        label_emb, title_x, rp_lt, cnt_lt, bkt_lt,
        Wl_tl, bl_tl, Wr_tl, out_title, NT);
}

// Round 17
// 1291.222 us; speedup vs baseline: 1.1414x; 1.1414x over previous
//
#include <hip/hip_runtime.h>
#include <hip/hip_bf16.h>

// GNN_84043920048593: hetero SAGEConv. f32 I/O.
// R14 best: 540us. R15 (dual-stream epi) 783us: L1 thrash. R16 (fused gather)
// 1474us: gather serialized per-wave. R17: exact R14 revert + ONE change:
// epi __launch_bounds__(256,8) (VGPR cap 64 = R14's natural alloc) to double
// occupancy and hide the A-load latency diagnosed in R14 (VALUBusy 35%).

typedef unsigned int u32;
typedef unsigned char u8;

__global__ void sentinel_kernel(float* out, int n) {
    int i = blockIdx.x * 256 + threadIdx.x;
    if (i < n) out[i] = 999.0f;
}

// ---------- CSR build (unchanged, validated R13) ----------------------------
__global__ void __launch_bounds__(256)
bin_hist_kernel(const int* __restrict__ dst, int* __restrict__ binhist,
                int n, int shift) {
    __shared__ int lh[256];
    int tid = threadIdx.x;
    lh[tid] = 0;
    __syncthreads();
    int base = blockIdx.x * 4096;
    #pragma unroll
    for (int k = 0; k < 16; ++k) {
        int e = base + k * 256 + tid;
        if (e < n) atomicAdd(&lh[dst[e] >> shift], 1);
    }
    __syncthreads();
    if (lh[tid] > 0) atomicAdd(binhist + tid, lh[tid]);
}

__global__ void __launch_bounds__(256)
bin_scan_kernel(const int* __restrict__ binhist, int* __restrict__ start,
                int* __restrict__ cur_bin, int nbins) {
    __shared__ int sh[256];
    int t = threadIdx.x;
    int v = (t < nbins) ? binhist[t] : 0;
    sh[t] = v;
    __syncthreads();
    for (int off = 1; off < 256; off <<= 1) {
        int u = (t >= off) ? sh[t - off] : 0;
        __syncthreads();
        sh[t] += u;
        __syncthreads();
    }
    if (t < nbins) { start[t] = sh[t] - v; cur_bin[t] = sh[t] - v; }
    if (t == 255) start[nbins] = sh[255];
}

__global__ void __launch_bounds__(256)
bin_scatter_kernel(const int* __restrict__ src, const int* __restrict__ dst,
                   const int* __restrict__ remap,
                   int* __restrict__ cur_bin, u32* __restrict__ staging,
                   int n, int shift) {
    __shared__ int lh[256], sc[256], lrp[256], lcur[256], lbase[256];
    __shared__ u32 stage[4096];
    __shared__ u8  sbin[4096];
    int tid = threadIdx.x;
    lh[tid] = 0;
    __syncthreads();
    int base = blockIdx.x * 4096;
    int mybin[16]; u32 mypk[16];
    int dmask = (1 << shift) - 1;
    #pragma unroll
    for (int k = 0; k < 16; ++k) {
        int e = base + k * 256 + tid;
        mybin[k] = -1;
        if (e < n) {
            int d = dst[e];
            int s = src[e];
            if (remap) s = remap[s];
            int b = d >> shift;
            mybin[k] = b;
            mypk[k] = ((u32)(d & dmask) << 18) | (u32)s;
            atomicAdd(&lh[b], 1);
        }
    }
    __syncthreads();
    int v = lh[tid];
    sc[tid] = v;
    __syncthreads();
    for (int off = 1; off < 256; off <<= 1) {
        int u = (tid >= off) ? sc[tid - off] : 0;
        __syncthreads();
        sc[tid] += u;
        __syncthreads();
    }
    lrp[tid] = sc[tid] - v;
    lcur[tid] = sc[tid] - v;
    if (v > 0) lbase[tid] = atomicAdd(&cur_bin[tid], v);
    __syncthreads();
    #pragma unroll
    for (int k = 0; k < 16; ++k) {
        if (mybin[k] >= 0) {
            int p = atomicAdd(&lcur[mybin[k]], 1);
            stage[p] = mypk[k];
            sbin[p] = (u8)mybin[k];
        }
    }
    __syncthreads();
    int cnt_here = min(4096, n - base);
    for (int i = tid; i < cnt_here; i += 256) {
        int b = sbin[i];
        staging[lbase[b] + (i - lrp[b])] = stage[i];
    }
}

__global__ void __launch_bounds__(256)
bin_build_kernel(const u32* __restrict__ staging, const int* __restrict__ start,
                 int* __restrict__ bucket, int* __restrict__ rp,
                 int* __restrict__ cnt, int shift, int n_dst) {
    __shared__ int fh[1024], frp[1024], fcur[1024], part[256];
    int tid = threadIdx.x;
    int b = blockIdx.x;
    int s0 = start[b], s1 = start[b + 1];
    int m = s1 - s0;
    int nd = 1 << shift;
    int dbase = b << shift;
    for (int j = tid; j < nd; j += 256) fh[j] = 0;
    __syncthreads();
    for (int i = tid; i < m; i += 256)
        atomicAdd(&fh[staging[s0 + i] >> 18], 1);
    __syncthreads();
    int K = nd >> 8;
    int t0 = tid * K;
    int s = 0;
    for (int k = 0; k < K; ++k) s += fh[t0 + k];
    part[tid] = s;
    __syncthreads();
    for (int off = 1; off < 256; off <<= 1) {
        int u = (tid >= off) ? part[tid - off] : 0;
        __syncthreads();
        part[tid] += u;
        __syncthreads();
    }
    int run = part[tid] - s;
    for (int k = 0; k < K; ++k) {
        frp[t0 + k] = run; fcur[t0 + k] = run;
        run += fh[t0 + k];
    }
    __syncthreads();
    for (int j = tid; j < nd; j += 256) {
        int d = dbase + j;
        if (d < n_dst) { rp[d] = s0 + frp[j]; cnt[d] = fh[j]; }
    }
    for (int i = tid; i < m; i += 256) {
        u32 pk = staging[s0 + i];
        int dl = pk >> 18;
        int p = atomicAdd(&fcur[dl], 1);
        bucket[s0 + p] = (int)(pk & 0x3FFFFu);
    }
}

// ---------- gather-reduce (unchanged, 1 row/wave) ---------------------------
__global__ void __launch_bounds__(256)
gather_mean_kernel(const float* __restrict__ x,
                   const int* __restrict__ rp,
                   const int* __restrict__ cnt,
                   const int* __restrict__ bucket,
                   float* __restrict__ agg,
                   int n_dst)
{
    int wave = threadIdx.x >> 6, lane = threadIdx.x & 63;
    int i = blockIdx.x * 4 + wave;
    if (i >= n_dst) return;
    int st = rp[i], deg = cnt[i];
    int q = lane >> 4, c = lane & 15;
    float4 acc = make_float4(0.f, 0.f, 0.f, 0.f);
    for (int j = 0; j < deg; j += 4) {
        int idx = j + q;
        int r = bucket[st + min(idx, deg - 1)];
        float m = (idx < deg) ? 1.0f : 0.0f;
        float4 v = ((const float4*)x)[(size_t)r * 16 + c];
        acc.x += m * v.x; acc.y += m * v.y;
        acc.z += m * v.z; acc.w += m * v.w;
    }
    acc.x += __shfl_xor(acc.x, 16); acc.y += __shfl_xor(acc.y, 16);
    acc.z += __shfl_xor(acc.z, 16); acc.w += __shfl_xor(acc.w, 16);
    acc.x += __shfl_xor(acc.x, 32); acc.y += __shfl_xor(acc.y, 32);
    acc.z += __shfl_xor(acc.z, 32); acc.w += __shfl_xor(acc.w, 32);
    if (q == 0) {
        float inv = 1.0f / fmaxf((float)deg, 1.0f);
        ((float4*)agg)[(size_t)i * 16 + c] =
            make_float4(acc.x * inv, acc.y * inv, acc.z * inv, acc.w * inv);
    }
}

// ---------- epilogues: R14 sequential-W phases, 8x4 tile, occupancy x2 ------
#define GEMM_OPERAND8(AROW, WLDS)                                           \
    for (int kb = 0; kb < 64; kb += 4) {                                    \
        float4 a[8];                                                        \
        _Pragma("unroll")                                                   \
        for (int r = 0; r < 8; ++r) a[r] = *(const float4*)((AROW(r)) + kb);\
        _Pragma("unroll")                                                   \
        for (int kk = 0; kk < 4; ++kk) {                                    \
            float4 w = *(const float4*)(&WLDS[kb + kk][j0]);                \
            _Pragma("unroll")                                               \
            for (int r = 0; r < 8; ++r) {                                   \
                float av = ((const float*)&a[r])[kk];                       \
                acc[r][0] += av * w.x; acc[r][1] += av * w.y;               \
                acc[r][2] += av * w.z; acc[r][3] += av * w.w;               \
            }                                                               \
        }                                                                   \
    }

#define LOAD_W1(Wp)                                                         \
    for (int idx = threadIdx.x; idx < 4096; idx += 256) {                   \
        int k = idx >> 6, j = idx & 63;                                     \
        wbuf[k][j] = (Wp)[j * 64 + k];                                      \
    }
#define LOAD_W2(Wp, Wq)                                                     \
    for (int idx = threadIdx.x; idx < 4096; idx += 256) {                   \
        int k = idx >> 6, j = idx & 63;                                     \
        wbuf[k][j] = (Wp)[j * 64 + k] + (Wq)[j * 64 + k];                   \
    }

__global__ void __launch_bounds__(256, 8)
epi_label_kernel(const float* __restrict__ agg_tl,
                 const float* __restrict__ agg_ll,
                 const float* __restrict__ xemb,
                 const int* __restrict__ nid,
                 const float* __restrict__ Wl_tl, const float* __restrict__ bl_tl,
                 const float* __restrict__ Wr_tl,
                 const float* __restrict__ Wl_ll, const float* __restrict__ bl_ll,
                 const float* __restrict__ Wr_ll,
                 float* __restrict__ out, int n)
{
    __shared__ float wbuf[64][64];   // 16 KB, reused per phase

    int ty = threadIdx.x >> 4, tx = threadIdx.x & 15;
    int i0 = blockIdx.x * 128 + ty * 8;
    int j0 = tx * 4;

    int rr[8], nd[8];
    #pragma unroll
    for (int r = 0; r < 8; ++r) rr[r] = min(i0 + r, n - 1);
    #pragma unroll
    for (int r = 0; r < 8; ++r) nd[r] = nid[rr[r]];

    float4 bias;
    bias.x = bl_tl[j0+0] + bl_ll[j0+0];
    bias.y = bl_tl[j0+1] + bl_ll[j0+1];
    bias.z = bl_tl[j0+2] + bl_ll[j0+2];
    bias.w = bl_tl[j0+3] + bl_ll[j0+3];
    float acc[8][4];
    #pragma unroll
    for (int r = 0; r < 8; ++r) {
        acc[r][0] = bias.x; acc[r][1] = bias.y;
        acc[r][2] = bias.z; acc[r][3] = bias.w;
    }

    // phase 0: Wl_tl^T * agg_tl
    LOAD_W1(Wl_tl)
    __syncthreads();
    #define A0(r) (agg_tl + (size_t)rr[r] * 64)
    GEMM_OPERAND8(A0, wbuf)
    #undef A0
    __syncthreads();

    // phase 1: Wl_ll^T * agg_ll
    LOAD_W1(Wl_ll)
    __syncthreads();
    #define A1(r) (agg_ll + (size_t)rr[r] * 64)
    GEMM_OPERAND8(A1, wbuf)
    #undef A1
    __syncthreads();

    // phase 2: (Wr_tl + Wr_ll)^T * x_label
    LOAD_W2(Wr_tl, Wr_ll)
    __syncthreads();
    #define A2(r) (xemb + (size_t)nd[r] * 64)
    GEMM_OPERAND8(A2, wbuf)
    #undef A2

    #pragma unroll
    for (int r = 0; r < 8; ++r) {
        if (i0 + r < n) {
            float4 o;
            o.x = fmaxf(acc[r][0], 0.0f); o.y = fmaxf(acc[r][1], 0.0f);
            o.z = fmaxf(acc[r][2], 0.0f); o.w = fmaxf(acc[r][3], 0.0f);
            *(float4*)(out + (size_t)(i0 + r) * 64 + j0) = o;
        }
    }
}

__global__ void __launch_bounds__(256, 8)
epi_title_kernel(const float* __restrict__ agg_lt,
                 const float* __restrict__ title_x,
                 const float* __restrict__ Wl_tl, const float* __restrict__ bl_tl,
                 const float* __restrict__ Wr_tl,
                 float* __restrict__ out, int n)
{
    __shared__ float wbuf[64][64];

    int ty = threadIdx.x >> 4, tx = threadIdx.x & 15;
    int i0 = blockIdx.x * 128 + ty * 8;
    int j0 = tx * 4;

    int rr[8];
    #pragma unroll
    for (int r = 0; r < 8; ++r) rr[r] = min(i0 + r, n - 1);

    float4 bias = *(const float4*)(bl_tl + j0);
    float acc[8][4];
    #pragma unroll
    for (int r = 0; r < 8; ++r) {
        acc[r][0] = bias.x; acc[r][1] = bias.y;
        acc[r][2] = bias.z; acc[r][3] = bias.w;
    }

    // phase 0: Wl_tl^T * agg_lt
    LOAD_W1(Wl_tl)
    __syncthreads();
    #define A0(r) (agg_lt + (size_t)rr[r] * 64)
    GEMM_OPERAND8(A0, wbuf)
    #undef A0
    __syncthreads();

    // phase 1: Wr_tl^T * title_x
    LOAD_W1(Wr_tl)
    __syncthreads();
    #define A1(r) (title_x + (size_t)rr[r] * 64)
    GEMM_OPERAND8(A1, wbuf)
    #undef A1

    #pragma unroll
    for (int r = 0; r < 8; ++r) {
        if (i0 + r < n) {
            float4 o;
            o.x = fmaxf(acc[r][0], 0.0f); o.y = fmaxf(acc[r][1], 0.0f);
            o.z = fmaxf(acc[r][2], 0.0f); o.w = fmaxf(acc[r][3], 0.0f);
            *(float4*)(out + (size_t)(i0 + r) * 64 + j0) = o;
        }
    }
}

extern "C" void kernel_launch(void* const* d_in, const int* in_sizes, int n_in,
                              void* d_out, int out_size, void* d_ws, size_t ws_size,
                              hipStream_t stream)
{
    const float* title_x   = (const float*)d_in[0];
    const float* label_emb = (const float*)d_in[1];
    const float* Wl_tl     = (const float*)d_in[2];
    const float* bl_tl     = (const float*)d_in[3];
    const float* Wr_tl     = (const float*)d_in[4];
    const float* Wl_ll     = (const float*)d_in[5];
    const float* bl_ll     = (const float*)d_in[6];
    const float* Wr_ll     = (const float*)d_in[7];
    const int* label_node_id = (const int*)d_in[8];
    const int* tl_src = (const int*)d_in[9];
    const int* tl_dst = (const int*)d_in[10];
    const int* lt_src = (const int*)d_in[11];
    const int* lt_dst = (const int*)d_in[12];
    const int* ll_src = (const int*)d_in[13];
    const int* ll_dst = (const int*)d_in[14];

    const int NT  = in_sizes[0] / 64;
    const int NL  = in_sizes[8];
    const int eTL = in_sizes[9];
    const int eLT = in_sizes[11];
    const int eLL = in_sizes[13];

    const int SH_L = 9,  NB_L = (NL + 511) >> 9;
    const int SH_T = 10, NB_T = (NT + 1023) >> 10;

    size_t szAgL = (size_t)NL * 64 * 4;
    size_t szAgT = (size_t)NT * 64 * 4;
    size_t iNL   = (size_t)NL * 4;
    size_t iNT   = (size_t)NT * 4;

    size_t regionA = 2 * szAgL + 4 * iNL + ((size_t)eTL + eLL) * 4;
    size_t regionB = szAgT + 2 * iNT + (size_t)eLT * 4;
    size_t big     = regionA > regionB ? regionA : regionB;
    size_t szSmall = (256 + 257 + 256) * 4;
    size_t needed  = big + szSmall;

    float* out_label = (float*)d_out;
    float* out_title = out_label + (size_t)NL * 64;

    if (ws_size < needed) {
        sentinel_kernel<<<(out_size + 255) / 256, 256, 0, stream>>>((float*)d_out, out_size);
        return;
    }

    char* base = (char*)d_ws;
    float* agg_tl  = (float*)(base);
    float* agg_ll  = (float*)(base + szAgL);
    u32*   stagA   = (u32*)  (base + szAgL);            // overlays agg_ll
    int* rp_tl  = (int*)(base + 2 * szAgL);
    int* cnt_tl = (int*)(base + 2 * szAgL + iNL);
    int* rp_ll  = (int*)(base + 2 * szAgL + 2 * iNL);
    int* cnt_ll = (int*)(base + 2 * szAgL + 3 * iNL);
    int* bkt_tl = (int*)(base + 2 * szAgL + 4 * iNL);
    int* bkt_ll = bkt_tl + eTL;
    float* agg_lt = (float*)(base);
    u32*   stagB  = (u32*)(base);                        // overlays agg_lt
    int* rp_lt  = (int*)(base + szAgT);
    int* cnt_lt = (int*)(base + szAgT + iNT);
    int* bkt_lt = (int*)(base + szAgT + 2 * iNT);
    int* binhist = (int*)(base + big);
    int* startb  = binhist + 256;
    int* curbin  = startb + 257;

    auto nchunk = [](int n) { return (n + 4095) / 4096; };

    auto build_csr = [&](const int* esrc, const int* edst, const int* remap,
                         u32* staging, int* bucket, int* rp, int* cnt,
                         int n_edges, int n_dst, int shift, int nbins) {
        (void)hipMemsetAsync(binhist, 0, nbins * 4, stream);
        bin_hist_kernel<<<nchunk(n_edges), 256, 0, stream>>>(edst, binhist, n_edges, shift);
        bin_scan_kernel<<<1, 256, 0, stream>>>(binhist, startb, curbin, nbins);
        bin_scatter_kernel<<<nchunk(n_edges), 256, 0, stream>>>(
            esrc, edst, remap, curbin, staging, n_edges, shift);
        bin_build_kernel<<<nbins, 256, 0, stream>>>(
            staging, startb, bucket, rp, cnt, shift, n_dst);
    };

    // ---- phase A: label destination ----------------------------------------
    build_csr(tl_src, tl_dst, nullptr,       stagA, bkt_tl, rp_tl, cnt_tl, eTL, NL, SH_L, NB_L);
    build_csr(ll_src, ll_dst, label_node_id, stagA, bkt_ll, rp_ll, cnt_ll, eLL, NL, SH_L, NB_L);
    gather_mean_kernel<<<(NL + 3) / 4, 256, 0, stream>>>(title_x,   rp_tl, cnt_tl, bkt_tl, agg_tl, NL);
    gather_mean_kernel<<<(NL + 3) / 4, 256, 0, stream>>>(label_emb, rp_ll, cnt_ll, bkt_ll, agg_ll, NL);
    epi_label_kernel<<<(NL + 127) / 128, 256, 0, stream>>>(
        agg_tl, agg_ll, label_emb, label_node_id,
        Wl_tl, bl_tl, Wr_tl, Wl_ll, bl_ll, Wr_ll, out_label, NL);

    // ---- phase B: title destination (stream-ordered reuse) -----------------
    build_csr(lt_src, lt_dst, label_node_id, stagB, bkt_lt, rp_lt, cnt_lt, eLT, NT, SH_T, NB_T);
    gather_mean_kernel<<<(NT + 3) / 4, 256, 0, stream>>>(label_emb, rp_lt, cnt_lt, bkt_lt, agg_lt, NT);
    epi_title_kernel<<<(NT + 127) / 128, 256, 0, stream>>>(
        agg_lt, title_x, Wl_tl, bl_tl, Wr_tl, out_title, NT);
}

// Round 18
// 539.006 us; speedup vs baseline: 2.7344x; 2.3956x over previous
//
#include <hip/hip_runtime.h>
#include <hip/hip_bf16.h>

// GNN_84043920048593: hetero SAGEConv. f32 I/O.
// R14 = measured best (540us). R15 (dual-stream) 783: L1 thrash. R16 (fused
// gather) 1474: serialized gather. R17 ((256,8)) 1291: VGPR forced to 32 ->
// spills (WRITE 913MB). R18: byte-exact R14 revert. Epi vector-f32 ceiling
// analysis: W-from-LDS GEMM caps ~44% VALU (LDS pipe 2.2x oversubscribed at
// 12 waves/CU); R14 runs at 0.8x that ceiling.

typedef unsigned int u32;
typedef unsigned char u8;

__global__ void sentinel_kernel(float* out, int n) {
    int i = blockIdx.x * 256 + threadIdx.x;
    if (i < n) out[i] = 999.0f;
}

// ---------- CSR build (validated R13) ---------------------------------------
__global__ void __launch_bounds__(256)
bin_hist_kernel(const int* __restrict__ dst, int* __restrict__ binhist,
                int n, int shift) {
    __shared__ int lh[256];
    int tid = threadIdx.x;
    lh[tid] = 0;
    __syncthreads();
    int base = blockIdx.x * 4096;
    #pragma unroll
    for (int k = 0; k < 16; ++k) {
        int e = base + k * 256 + tid;
        if (e < n) atomicAdd(&lh[dst[e] >> shift], 1);
    }
    __syncthreads();
    if (lh[tid] > 0) atomicAdd(binhist + tid, lh[tid]);
}

__global__ void __launch_bounds__(256)
bin_scan_kernel(const int* __restrict__ binhist, int* __restrict__ start,
                int* __restrict__ cur_bin, int nbins) {
    __shared__ int sh[256];
    int t = threadIdx.x;
    int v = (t < nbins) ? binhist[t] : 0;
    sh[t] = v;
    __syncthreads();
    for (int off = 1; off < 256; off <<= 1) {
        int u = (t >= off) ? sh[t - off] : 0;
        __syncthreads();
        sh[t] += u;
        __syncthreads();
    }
    if (t < nbins) { start[t] = sh[t] - v; cur_bin[t] = sh[t] - v; }
    if (t == 255) start[nbins] = sh[255];
}

__global__ void __launch_bounds__(256)
bin_scatter_kernel(const int* __restrict__ src, const int* __restrict__ dst,
                   const int* __restrict__ remap,
                   int* __restrict__ cur_bin, u32* __restrict__ staging,
                   int n, int shift) {
    __shared__ int lh[256], sc[256], lrp[256], lcur[256], lbase[256];
    __shared__ u32 stage[4096];
    __shared__ u8  sbin[4096];
    int tid = threadIdx.x;
    lh[tid] = 0;
    __syncthreads();
    int base = blockIdx.x * 4096;
    int mybin[16]; u32 mypk[16];
    int dmask = (1 << shift) - 1;
    #pragma unroll
    for (int k = 0; k < 16; ++k) {
        int e = base + k * 256 + tid;
        mybin[k] = -1;
        if (e < n) {
            int d = dst[e];
            int s = src[e];
            if (remap) s = remap[s];
            int b = d >> shift;
            mybin[k] = b;
            mypk[k] = ((u32)(d & dmask) << 18) | (u32)s;
            atomicAdd(&lh[b], 1);
        }
    }
    __syncthreads();
    int v = lh[tid];
    sc[tid] = v;
    __syncthreads();
    for (int off = 1; off < 256; off <<= 1) {
        int u = (tid >= off) ? sc[tid - off] : 0;
        __syncthreads();
        sc[tid] += u;
        __syncthreads();
    }
    lrp[tid] = sc[tid] - v;
    lcur[tid] = sc[tid] - v;
    if (v > 0) lbase[tid] = atomicAdd(&cur_bin[tid], v);
    __syncthreads();
    #pragma unroll
    for (int k = 0; k < 16; ++k) {
        if (mybin[k] >= 0) {
            int p = atomicAdd(&lcur[mybin[k]], 1);
            stage[p] = mypk[k];
            sbin[p] = (u8)mybin[k];
        }
    }
    __syncthreads();
    int cnt_here = min(4096, n - base);
    for (int i = tid; i < cnt_here; i += 256) {
        int b = sbin[i];
        staging[lbase[b] + (i - lrp[b])] = stage[i];
    }
}

__global__ void __launch_bounds__(256)
bin_build_kernel(const u32* __restrict__ staging, const int* __restrict__ start,
                 int* __restrict__ bucket, int* __restrict__ rp,
                 int* __restrict__ cnt, int shift, int n_dst) {
    __shared__ int fh[1024], frp[1024], fcur[1024], part[256];
    int tid = threadIdx.x;
    int b = blockIdx.x;
    int s0 = start[b], s1 = start[b + 1];
    int m = s1 - s0;
    int nd = 1 << shift;
    int dbase = b << shift;
    for (int j = tid; j < nd; j += 256) fh[j] = 0;
    __syncthreads();
    for (int i = tid; i < m; i += 256)
        atomicAdd(&fh[staging[s0 + i] >> 18], 1);
    __syncthreads();
    int K = nd >> 8;
    int t0 = tid * K;
    int s = 0;
    for (int k = 0; k < K; ++k) s += fh[t0 + k];
    part[tid] = s;
    __syncthreads();
    for (int off = 1; off < 256; off <<= 1) {
        int u = (tid >= off) ? part[tid - off] : 0;
        __syncthreads();
        part[tid] += u;
        __syncthreads();
    }
    int run = part[tid] - s;
    for (int k = 0; k < K; ++k) {
        frp[t0 + k] = run; fcur[t0 + k] = run;
        run += fh[t0 + k];
    }
    __syncthreads();
    for (int j = tid; j < nd; j += 256) {
        int d = dbase + j;
        if (d < n_dst) { rp[d] = s0 + frp[j]; cnt[d] = fh[j]; }
    }
    for (int i = tid; i < m; i += 256) {
        u32 pk = staging[s0 + i];
        int dl = pk >> 18;
        int p = atomicAdd(&fcur[dl], 1);
        bucket[s0 + p] = (int)(pk & 0x3FFFFu);
    }
}

// ---------- gather-reduce (1 row/wave) --------------------------------------
__global__ void __launch_bounds__(256)
gather_mean_kernel(const float* __restrict__ x,
                   const int* __restrict__ rp,
                   const int* __restrict__ cnt,
                   const int* __restrict__ bucket,
                   float* __restrict__ agg,
                   int n_dst)
{
    int wave = threadIdx.x >> 6, lane = threadIdx.x & 63;
    int i = blockIdx.x * 4 + wave;
    if (i >= n_dst) return;
    int st = rp[i], deg = cnt[i];
    int q = lane >> 4, c = lane & 15;
    float4 acc = make_float4(0.f, 0.f, 0.f, 0.f);
    for (int j = 0; j < deg; j += 4) {
        int idx = j + q;
        int r = bucket[st + min(idx, deg - 1)];
        float m = (idx < deg) ? 1.0f : 0.0f;
        float4 v = ((const float4*)x)[(size_t)r * 16 + c];
        acc.x += m * v.x; acc.y += m * v.y;
        acc.z += m * v.z; acc.w += m * v.w;
    }
    acc.x += __shfl_xor(acc.x, 16); acc.y += __shfl_xor(acc.y, 16);
    acc.z += __shfl_xor(acc.z, 16); acc.w += __shfl_xor(acc.w, 16);
    acc.x += __shfl_xor(acc.x, 32); acc.y += __shfl_xor(acc.y, 32);
    acc.z += __shfl_xor(acc.z, 32); acc.w += __shfl_xor(acc.w, 32);
    if (q == 0) {
        float inv = 1.0f / fmaxf((float)deg, 1.0f);
        ((float4*)agg)[(size_t)i * 16 + c] =
            make_float4(acc.x * inv, acc.y * inv, acc.z * inv, acc.w * inv);
    }
}

// ---------- epilogues: R14 sequential-W phases, 8x4 tile --------------------
#define GEMM_OPERAND8(AROW, WLDS)                                           \
    for (int kb = 0; kb < 64; kb += 4) {                                    \
        float4 a[8];                                                        \
        _Pragma("unroll")                                                   \
        for (int r = 0; r < 8; ++r) a[r] = *(const float4*)((AROW(r)) + kb);\
        _Pragma("unroll")                                                   \
        for (int kk = 0; kk < 4; ++kk) {                                    \
            float4 w = *(const float4*)(&WLDS[kb + kk][j0]);                \
            _Pragma("unroll")                                               \
            for (int r = 0; r < 8; ++r) {                                   \
                float av = ((const float*)&a[r])[kk];                       \
                acc[r][0] += av * w.x; acc[r][1] += av * w.y;               \
                acc[r][2] += av * w.z; acc[r][3] += av * w.w;               \
            }                                                               \
        }                                                                   \
    }

#define LOAD_W1(Wp)                                                         \
    for (int idx = threadIdx.x; idx < 4096; idx += 256) {                   \
        int k = idx >> 6, j = idx & 63;                                     \
        wbuf[k][j] = (Wp)[j * 64 + k];                                      \
    }
#define LOAD_W2(Wp, Wq)                                                     \
    for (int idx = threadIdx.x; idx < 4096; idx += 256) {                   \
        int k = idx >> 6, j = idx & 63;                                     \
        wbuf[k][j] = (Wp)[j * 64 + k] + (Wq)[j * 64 + k];                   \
    }

__global__ void __launch_bounds__(256, 4)
epi_label_kernel(const float* __restrict__ agg_tl,
                 const float* __restrict__ agg_ll,
                 const float* __restrict__ xemb,
                 const int* __restrict__ nid,
                 const float* __restrict__ Wl_tl, const float* __restrict__ bl_tl,
                 const float* __restrict__ Wr_tl,
                 const float* __restrict__ Wl_ll, const float* __restrict__ bl_ll,
                 const float* __restrict__ Wr_ll,
                 float* __restrict__ out, int n)
{
    __shared__ float wbuf[64][64];   // 16 KB, reused per phase

    int ty = threadIdx.x >> 4, tx = threadIdx.x & 15;
    int i0 = blockIdx.x * 128 + ty * 8;
    int j0 = tx * 4;

    int rr[8], nd[8];
    #pragma unroll
    for (int r = 0; r < 8; ++r) rr[r] = min(i0 + r, n - 1);
    #pragma unroll
    for (int r = 0; r < 8; ++r) nd[r] = nid[rr[r]];

    float4 bias;
    bias.x = bl_tl[j0+0] + bl_ll[j0+0];
    bias.y = bl_tl[j0+1] + bl_ll[j0+1];
    bias.z = bl_tl[j0+2] + bl_ll[j0+2];
    bias.w = bl_tl[j0+3] + bl_ll[j0+3];
    float acc[8][4];
    #pragma unroll
    for (int r = 0; r < 8; ++r) {
        acc[r][0] = bias.x; acc[r][1] = bias.y;
        acc[r][2] = bias.z; acc[r][3] = bias.w;
    }

    // phase 0: Wl_tl^T * agg_tl
    LOAD_W1(Wl_tl)
    __syncthreads();
    #define A0(r) (agg_tl + (size_t)rr[r] * 64)
    GEMM_OPERAND8(A0, wbuf)
    #undef A0
    __syncthreads();

    // phase 1: Wl_ll^T * agg_ll
    LOAD_W1(Wl_ll)
    __syncthreads();
    #define A1(r) (agg_ll + (size_t)rr[r] * 64)
    GEMM_OPERAND8(A1, wbuf)
    #undef A1
    __syncthreads();

    // phase 2: (Wr_tl + Wr_ll)^T * x_label
    LOAD_W2(Wr_tl, Wr_ll)
    __syncthreads();
    #define A2(r) (xemb + (size_t)nd[r] * 64)
    GEMM_OPERAND8(A2, wbuf)
    #undef A2

    #pragma unroll
    for (int r = 0; r < 8; ++r) {
        if (i0 + r < n) {
            float4 o;
            o.x = fmaxf(acc[r][0], 0.0f); o.y = fmaxf(acc[r][1], 0.0f);
            o.z = fmaxf(acc[r][2], 0.0f); o.w = fmaxf(acc[r][3], 0.0f);
            *(float4*)(out + (size_t)(i0 + r) * 64 + j0) = o;
        }
    }
}

__global__ void __launch_bounds__(256, 4)
epi_title_kernel(const float* __restrict__ agg_lt,
                 const float* __restrict__ title_x,
                 const float* __restrict__ Wl_tl, const float* __restrict__ bl_tl,
                 const float* __restrict__ Wr_tl,
                 float* __restrict__ out, int n)
{
    __shared__ float wbuf[64][64];

    int ty = threadIdx.x >> 4, tx = threadIdx.x & 15;
    int i0 = blockIdx.x * 128 + ty * 8;
    int j0 = tx * 4;

    int rr[8];
    #pragma unroll
    for (int r = 0; r < 8; ++r) rr[r] = min(i0 + r, n - 1);

    float4 bias = *(const float4*)(bl_tl + j0);
    float acc[8][4];
    #pragma unroll
    for (int r = 0; r < 8; ++r) {
        acc[r][0] = bias.x; acc[r][1] = bias.y;
        acc[r][2] = bias.z; acc[r][3] = bias.w;
    }

    // phase 0: Wl_tl^T * agg_lt
    LOAD_W1(Wl_tl)
    __syncthreads();
    #define A0(r) (agg_lt + (size_t)rr[r] * 64)
    GEMM_OPERAND8(A0, wbuf)
    #undef A0
    __syncthreads();

    // phase 1: Wr_tl^T * title_x
    LOAD_W1(Wr_tl)
    __syncthreads();
    #define A1(r) (title_x + (size_t)rr[r] * 64)
    GEMM_OPERAND8(A1, wbuf)
    #undef A1

    #pragma unroll
    for (int r = 0; r < 8; ++r) {
        if (i0 + r < n) {
            float4 o;
            o.x = fmaxf(acc[r][0], 0.0f); o.y = fmaxf(acc[r][1], 0.0f);
            o.z = fmaxf(acc[r][2], 0.0f); o.w = fmaxf(acc[r][3], 0.0f);
            *(float4*)(out + (size_t)(i0 + r) * 64 + j0) = o;
        }
    }
}

extern "C" void kernel_launch(void* const* d_in, const int* in_sizes, int n_in,
                              void* d_out, int out_size, void* d_ws, size_t ws_size,
                              hipStream_t stream)
{
    const float* title_x   = (const float*)d_in[0];
    const float* label_emb = (const float*)d_in[1];
    const float* Wl_tl     = (const float*)d_in[2];
    const float* bl_tl     = (const float*)d_in[3];
    const float* Wr_tl     = (const float*)d_in[4];
    const float* Wl_ll     = (const float*)d_in[5];
    const float* bl_ll     = (const float*)d_in[6];
    const float* Wr_ll     = (const float*)d_in[7];
    const int* label_node_id = (const int*)d_in[8];
    const int* tl_src = (const int*)d_in[9];
    const int* tl_dst = (const int*)d_in[10];
    const int* lt_src = (const int*)d_in[11];
    const int* lt_dst = (const int*)d_in[12];
    const int* ll_src = (const int*)d_in[13];
    const int* ll_dst = (const int*)d_in[14];

    const int NT  = in_sizes[0] / 64;
    const int NL  = in_sizes[8];
    const int eTL = in_sizes[9];
    const int eLT = in_sizes[11];
    const int eLL = in_sizes[13];

    const int SH_L = 9,  NB_L = (NL + 511) >> 9;
    const int SH_T = 10, NB_T = (NT + 1023) >> 10;

    size_t szAgL = (size_t)NL * 64 * 4;
    size_t szAgT = (size_t)NT * 64 * 4;
    size_t iNL   = (size_t)NL * 4;
    size_t iNT   = (size_t)NT * 4;

    size_t regionA = 2 * szAgL + 4 * iNL + ((size_t)eTL + eLL) * 4;
    size_t regionB = szAgT + 2 * iNT + (size_t)eLT * 4;
    size_t big     = regionA > regionB ? regionA : regionB;
    size_t szSmall = (256 + 257 + 256) * 4;
    size_t needed  = big + szSmall;

    float* out_label = (float*)d_out;
    float* out_title = out_label + (size_t)NL * 64;

    if (ws_size < needed) {
        sentinel_kernel<<<(out_size + 255) / 256, 256, 0, stream>>>((float*)d_out, out_size);
        return;
    }

    char* base = (char*)d_ws;
    float* agg_tl  = (float*)(base);
    float* agg_ll  = (float*)(base + szAgL);
    u32*   stagA   = (u32*)  (base + szAgL);            // overlays agg_ll
    int* rp_tl  = (int*)(base + 2 * szAgL);
    int* cnt_tl = (int*)(base + 2 * szAgL + iNL);
    int* rp_ll  = (int*)(base + 2 * szAgL + 2 * iNL);
    int* cnt_ll = (int*)(base + 2 * szAgL + 3 * iNL);
    int* bkt_tl = (int*)(base + 2 * szAgL + 4 * iNL);
    int* bkt_ll = bkt_tl + eTL;
    float* agg_lt = (float*)(base);
    u32*   stagB  = (u32*)(base);                        // overlays agg_lt
    int* rp_lt  = (int*)(base + szAgT);
    int* cnt_lt = (int*)(base + szAgT + iNT);
    int* bkt_lt = (int*)(base + szAgT + 2 * iNT);
    int* binhist = (int*)(base + big);
    int* startb  = binhist + 256;
    int* curbin  = startb + 257;

    auto nchunk = [](int n) { return (n + 4095) / 4096; };

    auto build_csr = [&](const int* esrc, const int* edst, const int* remap,
                         u32* staging, int* bucket, int* rp, int* cnt,
                         int n_edges, int n_dst, int shift, int nbins) {
        (void)hipMemsetAsync(binhist, 0, nbins * 4, stream);
        bin_hist_kernel<<<nchunk(n_edges), 256, 0, stream>>>(edst, binhist, n_edges, shift);
        bin_scan_kernel<<<1, 256, 0, stream>>>(binhist, startb, curbin, nbins);
        bin_scatter_kernel<<<nchunk(n_edges), 256, 0, stream>>>(
            esrc, edst, remap, curbin, staging, n_edges, shift);
        bin_build_kernel<<<nbins, 256, 0, stream>>>(
            staging, startb, bucket, rp, cnt, shift, n_dst);
    };

    // ---- phase A: label destination ----------------------------------------
    build_csr(tl_src, tl_dst, nullptr,       stagA, bkt_tl, rp_tl, cnt_tl, eTL, NL, SH_L, NB_L);
    build_csr(ll_src, ll_dst, label_node_id, stagA, bkt_ll, rp_ll, cnt_ll, eLL, NL, SH_L, NB_L);
    gather_mean_kernel<<<(NL + 3) / 4, 256, 0, stream>>>(title_x,   rp_tl, cnt_tl, bkt_tl, agg_tl, NL);
    gather_mean_kernel<<<(NL + 3) / 4, 256, 0, stream>>>(label_emb, rp_ll, cnt_ll, bkt_ll, agg_ll, NL);
    epi_label_kernel<<<(NL + 127) / 128, 256, 0, stream>>>(
        agg_tl, agg_ll, label_emb, label_node_id,
        Wl_tl, bl_tl, Wr_tl, Wl_ll, bl_ll, Wr_ll, out_label, NL);

    // ---- phase B: title destination (stream-ordered reuse) -----------------
    build_csr(lt_src, lt_dst, label_node_id, stagB, bkt_lt, rp_lt, cnt_lt, eLT, NT, SH_T, NB_T);
    gather_mean_kernel<<<(NT + 3) / 4, 256, 0, stream>>>(label_emb, rp_lt, cnt_lt, bkt_lt, agg_lt, NT);
    epi_title_kernel<<<(NT + 127) / 128, 256, 0, stream>>>(
        agg_lt, title_x, Wl_tl, bl_tl, Wr_tl, out_title, NT);
}

// Round 19
// 409.444 us; speedup vs baseline: 3.5996x; 1.3164x over previous
//
#include <hip/hip_runtime.h>
#include <hip/hip_bf16.h>

// GNN_84043920048593: hetero SAGEConv. f32 I/O.
// R18 = banked baseline 539us (CSR build + wave-gather + vector-f32 epis).
// Epis pinned at vector-f32 LDS-fed ceiling (~35% VALU). R19: MFMA bf16
// epilogues — mfma_f32_16x16x32_bf16, A+W staged to bf16 LDS (pad 72),
// wave = 16-row strip, acc init = bias. Accuracy budget: bf16 adds ~2e-2
// absmax worst case vs 0.069 threshold.

typedef unsigned int u32;
typedef unsigned char u8;
typedef short short8 __attribute__((ext_vector_type(8)));
typedef float f32x4 __attribute__((ext_vector_type(4)));

__device__ __forceinline__ unsigned short f2bf(float f) {
    union { float f; u32 i; } v; v.f = f;
    u32 x = v.i; x += 0x7fffu + ((x >> 16) & 1u);
    return (unsigned short)(x >> 16);
}

__global__ void sentinel_kernel(float* out, int n) {
    int i = blockIdx.x * 256 + threadIdx.x;
    if (i < n) out[i] = 999.0f;
}

// ---------- CSR build (validated R13) ---------------------------------------
__global__ void __launch_bounds__(256)
bin_hist_kernel(const int* __restrict__ dst, int* __restrict__ binhist,
                int n, int shift) {
    __shared__ int lh[256];
    int tid = threadIdx.x;
    lh[tid] = 0;
    __syncthreads();
    int base = blockIdx.x * 4096;
    #pragma unroll
    for (int k = 0; k < 16; ++k) {
        int e = base + k * 256 + tid;
        if (e < n) atomicAdd(&lh[dst[e] >> shift], 1);
    }
    __syncthreads();
    if (lh[tid] > 0) atomicAdd(binhist + tid, lh[tid]);
}

__global__ void __launch_bounds__(256)
bin_scan_kernel(const int* __restrict__ binhist, int* __restrict__ start,
                int* __restrict__ cur_bin, int nbins) {
    __shared__ int sh[256];
    int t = threadIdx.x;
    int v = (t < nbins) ? binhist[t] : 0;
    sh[t] = v;
    __syncthreads();
    for (int off = 1; off < 256; off <<= 1) {
        int u = (t >= off) ? sh[t - off] : 0;
        __syncthreads();
        sh[t] += u;
        __syncthreads();
    }
    if (t < nbins) { start[t] = sh[t] - v; cur_bin[t] = sh[t] - v; }
    if (t == 255) start[nbins] = sh[255];
}

__global__ void __launch_bounds__(256)
bin_scatter_kernel(const int* __restrict__ src, const int* __restrict__ dst,
                   const int* __restrict__ remap,
                   int* __restrict__ cur_bin, u32* __restrict__ staging,
                   int n, int shift) {
    __shared__ int lh[256], sc[256], lrp[256], lcur[256], lbase[256];
    __shared__ u32 stage[4096];
    __shared__ u8  sbin[4096];
    int tid = threadIdx.x;
    lh[tid] = 0;
    __syncthreads();
    int base = blockIdx.x * 4096;
    int mybin[16]; u32 mypk[16];
    int dmask = (1 << shift) - 1;
    #pragma unroll
    for (int k = 0; k < 16; ++k) {
        int e = base + k * 256 + tid;
        mybin[k] = -1;
        if (e < n) {
            int d = dst[e];
            int s = src[e];
            if (remap) s = remap[s];
            int b = d >> shift;
            mybin[k] = b;
            mypk[k] = ((u32)(d & dmask) << 18) | (u32)s;
            atomicAdd(&lh[b], 1);
        }
    }
    __syncthreads();
    int v = lh[tid];
    sc[tid] = v;
    __syncthreads();
    for (int off = 1; off < 256; off <<= 1) {
        int u = (tid >= off) ? sc[tid - off] : 0;
        __syncthreads();
        sc[tid] += u;
        __syncthreads();
    }
    lrp[tid] = sc[tid] - v;
    lcur[tid] = sc[tid] - v;
    if (v > 0) lbase[tid] = atomicAdd(&cur_bin[tid], v);
    __syncthreads();
    #pragma unroll
    for (int k = 0; k < 16; ++k) {
        if (mybin[k] >= 0) {
            int p = atomicAdd(&lcur[mybin[k]], 1);
            stage[p] = mypk[k];
            sbin[p] = (u8)mybin[k];
        }
    }
    __syncthreads();
    int cnt_here = min(4096, n - base);
    for (int i = tid; i < cnt_here; i += 256) {
        int b = sbin[i];
        staging[lbase[b] + (i - lrp[b])] = stage[i];
    }
}

__global__ void __launch_bounds__(256)
bin_build_kernel(const u32* __restrict__ staging, const int* __restrict__ start,
                 int* __restrict__ bucket, int* __restrict__ rp,
                 int* __restrict__ cnt, int shift, int n_dst) {
    __shared__ int fh[1024], frp[1024], fcur[1024], part[256];
    int tid = threadIdx.x;
    int b = blockIdx.x;
    int s0 = start[b], s1 = start[b + 1];
    int m = s1 - s0;
    int nd = 1 << shift;
    int dbase = b << shift;
    for (int j = tid; j < nd; j += 256) fh[j] = 0;
    __syncthreads();
    for (int i = tid; i < m; i += 256)
        atomicAdd(&fh[staging[s0 + i] >> 18], 1);
    __syncthreads();
    int K = nd >> 8;
    int t0 = tid * K;
    int s = 0;
    for (int k = 0; k < K; ++k) s += fh[t0 + k];
    part[tid] = s;
    __syncthreads();
    for (int off = 1; off < 256; off <<= 1) {
        int u = (tid >= off) ? part[tid - off] : 0;
        __syncthreads();
        part[tid] += u;
        __syncthreads();
    }
    int run = part[tid] - s;
    for (int k = 0; k < K; ++k) {
        frp[t0 + k] = run; fcur[t0 + k] = run;
        run += fh[t0 + k];
    }
    __syncthreads();
    for (int j = tid; j < nd; j += 256) {
        int d = dbase + j;
        if (d < n_dst) { rp[d] = s0 + frp[j]; cnt[d] = fh[j]; }
    }
    for (int i = tid; i < m; i += 256) {
        u32 pk = staging[s0 + i];
        int dl = pk >> 18;
        int p = atomicAdd(&fcur[dl], 1);
        bucket[s0 + p] = (int)(pk & 0x3FFFFu);
    }
}

// ---------- gather-reduce (1 row/wave) --------------------------------------
__global__ void __launch_bounds__(256)
gather_mean_kernel(const float* __restrict__ x,
                   const int* __restrict__ rp,
                   const int* __restrict__ cnt,
                   const int* __restrict__ bucket,
                   float* __restrict__ agg,
                   int n_dst)
{
    int wave = threadIdx.x >> 6, lane = threadIdx.x & 63;
    int i = blockIdx.x * 4 + wave;
    if (i >= n_dst) return;
    int st = rp[i], deg = cnt[i];
    int q = lane >> 4, c = lane & 15;
    float4 acc = make_float4(0.f, 0.f, 0.f, 0.f);
    for (int j = 0; j < deg; j += 4) {
        int idx = j + q;
        int r = bucket[st + min(idx, deg - 1)];
        float m = (idx < deg) ? 1.0f : 0.0f;
        float4 v = ((const float4*)x)[(size_t)r * 16 + c];
        acc.x += m * v.x; acc.y += m * v.y;
        acc.z += m * v.z; acc.w += m * v.w;
    }
    acc.x += __shfl_xor(acc.x, 16); acc.y += __shfl_xor(acc.y, 16);
    acc.z += __shfl_xor(acc.z, 16); acc.w += __shfl_xor(acc.w, 16);
    acc.x += __shfl_xor(acc.x, 32); acc.y += __shfl_xor(acc.y, 32);
    acc.z += __shfl_xor(acc.z, 32); acc.w += __shfl_xor(acc.w, 32);
    if (q == 0) {
        float inv = 1.0f / fmaxf((float)deg, 1.0f);
        ((float4*)agg)[(size_t)i * 16 + c] =
            make_float4(acc.x * inv, acc.y * inv, acc.z * inv, acc.w * inv);
    }
}

// ---------- MFMA epilogues --------------------------------------------------
// mfma_f32_16x16x32_bf16 fragments:
//   A[m][k]: m = lane&15, k = (lane>>4)*8 + b        (b = 0..7)
//   B[k][j]: j = lane&15, k = (lane>>4)*8 + b        (B[k][j] = W[j][k])
//   D[r][c]: c = lane&15, r = (lane>>4)*4 + reg      (HW-verified, guide §3)
// A and W staged to bf16 LDS with row pad 72 (144B stride -> 2-way max).

// stage 64 node rows (clamped) as bf16 into a[64][72]
#define STAGE_A(DST, SRCPTR_EXPR)                                           \
    for (int idx = threadIdx.x; idx < 4096; idx += 256) {                   \
        int r = idx >> 6, k = idx & 63;                                     \
        DST[r][k] = f2bf((SRCPTR_EXPR)[k]);                                 \
    }
#define STAGE_W1(DST, Wp)                                                   \
    for (int idx = threadIdx.x; idx < 4096; idx += 256) {                   \
        int j = idx >> 6, k = idx & 63;                                     \
        DST[j][k] = f2bf((Wp)[idx]);                                        \
    }
#define STAGE_W2(DST, Wp, Wq)                                               \
    for (int idx = threadIdx.x; idx < 4096; idx += 256) {                   \
        int j = idx >> 6, k = idx & 63;                                     \
        DST[j][k] = f2bf((Wp)[idx] + (Wq)[idx]);                            \
    }

// one phase: acc[nt] += A_lds(strip) x W_lds^T  (8 mfma per wave)
#define MFMA_PHASE(ALDS, WLDS)                                              \
    _Pragma("unroll")                                                       \
    for (int kc = 0; kc < 2; ++kc) {                                        \
        short8 af = *(const short8*)&ALDS[lr0 + m][kc * 32 + kg * 8];       \
        _Pragma("unroll")                                                   \
        for (int nt = 0; nt < 4; ++nt) {                                    \
            short8 bf = *(const short8*)&WLDS[nt * 16 + m][kc * 32 + kg * 8];\
            acc[nt] = __builtin_amdgcn_mfma_f32_16x16x32_bf16(af, bf, acc[nt], 0, 0, 0); \
        }                                                                   \
    }

__global__ void __launch_bounds__(256)
epi_label_kernel(const float* __restrict__ agg_tl,
                 const float* __restrict__ agg_ll,
                 const float* __restrict__ xemb,
                 const int* __restrict__ nid,
                 const float* __restrict__ Wl_tl, const float* __restrict__ bl_tl,
                 const float* __restrict__ Wr_tl,
                 const float* __restrict__ Wl_ll, const float* __restrict__ bl_ll,
                 const float* __restrict__ Wr_ll,
                 float* __restrict__ out, int n)
{
    __shared__ short wa[64][72];     // A strip, bf16
    __shared__ short w0[64][72];     // W buffer 0 (Wl_tl, later Wr-sum)
    __shared__ short w1[64][72];     // W buffer 1 (Wl_ll)
    __shared__ int   ndl[64];

    int tid = threadIdx.x;
    int base = blockIdx.x * 64;
    int lane = tid & 63;
    int m = lane & 15, kg = lane >> 4;
    int lr0 = (tid >> 6) * 16;       // wave's strip start (local row)

    if (tid < 64) ndl[tid] = nid[min(base + tid, n - 1)];
    STAGE_W1(w0, Wl_tl)
    STAGE_W1(w1, Wl_ll)
    STAGE_A(wa, agg_tl + (size_t)min(base + (idx >> 6), n - 1) * 64)
    __syncthreads();

    f32x4 acc[4];
    #pragma unroll
    for (int nt = 0; nt < 4; ++nt) {
        float b = bl_tl[nt * 16 + m] + bl_ll[nt * 16 + m];
        acc[nt] = (f32x4){b, b, b, b};
    }

    MFMA_PHASE(wa, w0)               // agg_tl x Wl_tl^T
    __syncthreads();
    STAGE_A(wa, agg_ll + (size_t)min(base + (idx >> 6), n - 1) * 64)
    __syncthreads();
    MFMA_PHASE(wa, w1)               // agg_ll x Wl_ll^T
    __syncthreads();
    STAGE_W2(w0, Wr_tl, Wr_ll)
    STAGE_A(wa, xemb + (size_t)ndl[idx >> 6] * 64)
    __syncthreads();
    MFMA_PHASE(wa, w0)               // x_label x (Wr_tl+Wr_ll)^T

    #pragma unroll
    for (int nt = 0; nt < 4; ++nt) {
        #pragma unroll
        for (int j = 0; j < 4; ++j) {
            int gi = base + lr0 + kg * 4 + j;
            if (gi < n)
                out[(size_t)gi * 64 + nt * 16 + m] = fmaxf(acc[nt][j], 0.0f);
        }
    }
}

__global__ void __launch_bounds__(256)
epi_title_kernel(const float* __restrict__ agg_lt,
                 const float* __restrict__ title_x,
                 const float* __restrict__ Wl_tl, const float* __restrict__ bl_tl,
                 const float* __restrict__ Wr_tl,
                 float* __restrict__ out, int n)
{
    __shared__ short wa[64][72];
    __shared__ short w0[64][72];
    __shared__ short w1[64][72];

    int tid = threadIdx.x;
    int base = blockIdx.x * 64;
    int lane = tid & 63;
    int m = lane & 15, kg = lane >> 4;
    int lr0 = (tid >> 6) * 16;

    STAGE_W1(w0, Wl_tl)
    STAGE_W1(w1, Wr_tl)
    STAGE_A(wa, agg_lt + (size_t)min(base + (idx >> 6), n - 1) * 64)
    __syncthreads();

    f32x4 acc[4];
    #pragma unroll
    for (int nt = 0; nt < 4; ++nt) {
        float b = bl_tl[nt * 16 + m];
        acc[nt] = (f32x4){b, b, b, b};
    }

    MFMA_PHASE(wa, w0)               // agg_lt x Wl_tl^T
    __syncthreads();
    STAGE_A(wa, title_x + (size_t)min(base + (idx >> 6), n - 1) * 64)
    __syncthreads();
    MFMA_PHASE(wa, w1)               // title_x x Wr_tl^T

    #pragma unroll
    for (int nt = 0; nt < 4; ++nt) {
        #pragma unroll
        for (int j = 0; j < 4; ++j) {
            int gi = base + lr0 + kg * 4 + j;
            if (gi < n)
                out[(size_t)gi * 64 + nt * 16 + m] = fmaxf(acc[nt][j], 0.0f);
        }
    }
}

extern "C" void kernel_launch(void* const* d_in, const int* in_sizes, int n_in,
                              void* d_out, int out_size, void* d_ws, size_t ws_size,
                              hipStream_t stream)
{
    const float* title_x   = (const float*)d_in[0];
    const float* label_emb = (const float*)d_in[1];
    const float* Wl_tl     = (const float*)d_in[2];
    const float* bl_tl     = (const float*)d_in[3];
    const float* Wr_tl     = (const float*)d_in[4];
    const float* Wl_ll     = (const float*)d_in[5];
    const float* bl_ll     = (const float*)d_in[6];
    const float* Wr_ll     = (const float*)d_in[7];
    const int* label_node_id = (const int*)d_in[8];
    const int* tl_src = (const int*)d_in[9];
    const int* tl_dst = (const int*)d_in[10];
    const int* lt_src = (const int*)d_in[11];
    const int* lt_dst = (const int*)d_in[12];
    const int* ll_src = (const int*)d_in[13];
    const int* ll_dst = (const int*)d_in[14];

    const int NT  = in_sizes[0] / 64;
    const int NL  = in_sizes[8];
    const int eTL = in_sizes[9];
    const int eLT = in_sizes[11];
    const int eLL = in_sizes[13];

    const int SH_L = 9,  NB_L = (NL + 511) >> 9;
    const int SH_T = 10, NB_T = (NT + 1023) >> 10;

    size_t szAgL = (size_t)NL * 64 * 4;
    size_t szAgT = (size_t)NT * 64 * 4;
    size_t iNL   = (size_t)NL * 4;
    size_t iNT   = (size_t)NT * 4;

    size_t regionA = 2 * szAgL + 4 * iNL + ((size_t)eTL + eLL) * 4;
    size_t regionB = szAgT + 2 * iNT + (size_t)eLT * 4;
    size_t big     = regionA > regionB ? regionA : regionB;
    size_t szSmall = (256 + 257 + 256) * 4;
    size_t needed  = big + szSmall;

    float* out_label = (float*)d_out;
    float* out_title = out_label + (size_t)NL * 64;

    if (ws_size < needed) {
        sentinel_kernel<<<(out_size + 255) / 256, 256, 0, stream>>>((float*)d_out, out_size);
        return;
    }

    char* base = (char*)d_ws;
    float* agg_tl  = (float*)(base);
    float* agg_ll  = (float*)(base + szAgL);
    u32*   stagA   = (u32*)  (base + szAgL);            // overlays agg_ll
    int* rp_tl  = (int*)(base + 2 * szAgL);
    int* cnt_tl = (int*)(base + 2 * szAgL + iNL);
    int* rp_ll  = (int*)(base + 2 * szAgL + 2 * iNL);
    int* cnt_ll = (int*)(base + 2 * szAgL + 3 * iNL);
    int* bkt_tl = (int*)(base + 2 * szAgL + 4 * iNL);
    int* bkt_ll = bkt_tl + eTL;
    float* agg_lt = (float*)(base);
    u32*   stagB  = (u32*)(base);                        // overlays agg_lt
    int* rp_lt  = (int*)(base + szAgT);
    int* cnt_lt = (int*)(base + szAgT + iNT);
    int* bkt_lt = (int*)(base + szAgT + 2 * iNT);
    int* binhist = (int*)(base + big);
    int* startb  = binhist + 256;
    int* curbin  = startb + 257;

    auto nchunk = [](int n) { return (n + 4095) / 4096; };

    auto build_csr = [&](const int* esrc, const int* edst, const int* remap,
                         u32* staging, int* bucket, int* rp, int* cnt,
                         int n_edges, int n_dst, int shift, int nbins) {
        (void)hipMemsetAsync(binhist, 0, nbins * 4, stream);
        bin_hist_kernel<<<nchunk(n_edges), 256, 0, stream>>>(edst, binhist, n_edges, shift);
        bin_scan_kernel<<<1, 256, 0, stream>>>(binhist, startb, curbin, nbins);
        bin_scatter_kernel<<<nchunk(n_edges), 256, 0, stream>>>(
            esrc, edst, remap, curbin, staging, n_edges, shift);
        bin_build_kernel<<<nbins, 256, 0, stream>>>(
            staging, startb, bucket, rp, cnt, shift, n_dst);
    };

    // ---- phase A: label destination ----------------------------------------
    build_csr(tl_src, tl_dst, nullptr,       stagA, bkt_tl, rp_tl, cnt_tl, eTL, NL, SH_L, NB_L);
    build_csr(ll_src, ll_dst, label_node_id, stagA, bkt_ll, rp_ll, cnt_ll, eLL, NL, SH_L, NB_L);
    gather_mean_kernel<<<(NL + 3) / 4, 256, 0, stream>>>(title_x,   rp_tl, cnt_tl, bkt_tl, agg_tl, NL);
    gather_mean_kernel<<<(NL + 3) / 4, 256, 0, stream>>>(label_emb, rp_ll, cnt_ll, bkt_ll, agg_ll, NL);
    epi_label_kernel<<<(NL + 63) / 64, 256, 0, stream>>>(
        agg_tl, agg_ll, label_emb, label_node_id,
        Wl_tl, bl_tl, Wr_tl, Wl_ll, bl_ll, Wr_ll, out_label, NL);

    // ---- phase B: title destination (stream-ordered reuse) -----------------
    build_csr(lt_src, lt_dst, label_node_id, stagB, bkt_lt, rp_lt, cnt_lt, eLT, NT, SH_T, NB_T);
    gather_mean_kernel<<<(NT + 3) / 4, 256, 0, stream>>>(label_emb, rp_lt, cnt_lt, bkt_lt, agg_lt, NT);
    epi_title_kernel<<<(NT + 63) / 64, 256, 0, stream>>>(
        agg_lt, title_x, Wl_tl, bl_tl, Wr_tl, out_title, NT);
}